// Round 8
// baseline (466.375 us; speedup 1.0000x reference)
//
#include <hip/hip_runtime.h>
#include <hip/hip_bf16.h>

typedef __bf16 bf16;
typedef __attribute__((ext_vector_type(8))) __bf16 bf16x8;
typedef __attribute__((ext_vector_type(4))) __bf16 bf16x4;
typedef __attribute__((ext_vector_type(2))) __bf16 bf16x2;
typedef __attribute__((ext_vector_type(4))) float f32x4;

#define IN_F 512
#define OUT_F 128
#define BM 64
#define BK 64
#define NKT (IN_F / BK)
#define RPW 8       // rows per wave (scatter)
#define WPB 4       // waves per scatter block
#define PAGE 256    // edges staged per wave page
#define UNR 16
#define GEMM_REP 6  // instrumentation: x6 internal repeat (identical output)
#define SCAT_REP 4  // instrumentation: x4 internal repeat (identical output)

// ---- kernel 1: pack W into MFMA-fragment order ----------------------------
__global__ __launch_bounds__(256) void wt_convert_kernel(const float* __restrict__ w,
                                                         bf16* __restrict__ wt_frag) {
    int o = blockIdx.x * 256 + threadIdx.x;     // 0..65535
    int e   = o & 7;
    int l   = (o >> 3) & 63;
    int nb  = (o >> 9) & 7;
    int kkt = o >> 12;                          // kt*2+kk, 0..15
    int n = nb * 16 + (l & 15);
    int k = (kkt >> 1) * 64 + (kkt & 1) * 32 + (l >> 4) * 8 + e;
    wt_frag[o] = (bf16)w[k * OUT_F + n];
}

// ---- kernel 1b: row_ptr[r] = first edge index with adj_row >= r -----------
__global__ __launch_bounds__(256) void row_ptr_kernel(const int* __restrict__ adj_row,
                                                      int* __restrict__ row_ptr,
                                                      int n_edges, int n_nodes) {
    int e = blockIdx.x * 256 + threadIdx.x;
    if (e >= n_edges) return;
    int r1 = adj_row[e];
    int r0 = (e == 0) ? -1 : adj_row[e - 1];
    for (int r = r0 + 1; r <= r1; ++r) row_ptr[r] = e;
    if (e == n_edges - 1)
        for (int r = r1 + 1; r <= n_nodes; ++r) row_ptr[r] = n_edges;
}

// ---- kernel 2 (x6 instrumented): support = bf16(x @ W) ---------------------
// Identical structure to round 7; whole computation repeated GEMM_REP times,
// each rep recomputes acc from zero and stores the same support values.
__global__ __launch_bounds__(256) void gemm_x6_kernel(const float* __restrict__ x,
                                                      const bf16* __restrict__ wt_frag,
                                                      bf16* __restrict__ support,
                                                      int n_nodes) {
    __shared__ bf16 As[2][BM * BK];     // 2 x 8 KB

    const int tid  = threadIdx.x;
    const int lane = tid & 63;
    const int wid  = tid >> 6;          // wave owns cols [wid*32, wid*32+32)
    const int row0 = blockIdx.x * BM;

    float4 av[4];   // staged A (fp32)

    auto load_tile = [&](int kt) {
        const int k0 = kt * BK;
        #pragma unroll
        for (int i = 0; i < 4; ++i) {           // A: 64 rows x 16 float4
            int li = i * 256 + tid;
            int r = li >> 4, c4 = li & 15;
            int grow = row0 + r;
            float4 v = {0.f, 0.f, 0.f, 0.f};
            if (grow < n_nodes)
                v = *reinterpret_cast<const float4*>(x + (size_t)grow * IN_F + k0 + c4 * 4);
            av[i] = v;
        }
    };

    auto write_tile = [&](int buf) {
        char* Ab = (char*)As[buf];
        #pragma unroll
        for (int i = 0; i < 4; ++i) {
            int li = i * 256 + tid;
            int r = li >> 4, c4 = li & 15;
            bf16x4 b;
            b[0] = (bf16)av[i].x; b[1] = (bf16)av[i].y;
            b[2] = (bf16)av[i].z; b[3] = (bf16)av[i].w;
            *reinterpret_cast<bf16x4*>(Ab + ((r * 128 + c4 * 8) ^ ((r & 7) << 4))) = b;
        }
    };

    for (int rep = 0; rep < GEMM_REP; ++rep) {
        load_tile(0);
        write_tile(0);
        __syncthreads();

        f32x4 acc[4][2] = {};

        for (int kt = 0; kt < NKT; ++kt) {
            const int cur = kt & 1;

            bf16x8 b[2][2];
            #pragma unroll
            for (int kk = 0; kk < 2; ++kk)
                #pragma unroll
                for (int n = 0; n < 2; ++n) {
                    int f = (kt * 2 + kk) * 8 + (wid * 2 + n);
                    b[kk][n] = *reinterpret_cast<const bf16x8*>(wt_frag + ((size_t)f * 64 + lane) * 8);
                }

            if (kt < NKT - 1) load_tile(kt + 1);

            const char* Ab = (const char*)As[cur];
            #pragma unroll
            for (int kk = 0; kk < 2; ++kk) {
                const int kbyte = kk * 64 + (lane >> 4) * 16;
                bf16x8 a[4];
                #pragma unroll
                for (int m = 0; m < 4; ++m) {
                    int r = m * 16 + (lane & 15);
                    a[m] = *reinterpret_cast<const bf16x8*>(Ab + ((r * 128 + kbyte) ^ ((r & 7) << 4)));
                }
                #pragma unroll
                for (int m = 0; m < 4; ++m)
                    #pragma unroll
                    for (int n = 0; n < 2; ++n)
                        acc[m][n] = __builtin_amdgcn_mfma_f32_16x16x32_bf16(a[m], b[kk][n], acc[m][n], 0, 0, 0);
            }

            if (kt < NKT - 1) {
                write_tile(cur ^ 1);
                __syncthreads();
            }
        }

        // epilogue each rep (identical values -> idempotent)
        #pragma unroll
        for (int m = 0; m < 4; ++m) {
            #pragma unroll
            for (int n = 0; n < 2; ++n) {
                #pragma unroll
                for (int j = 0; j < 4; ++j) {
                    int gm = row0 + m * 16 + (lane >> 4) * 4 + j;
                    int gn = wid * 32 + n * 16 + (lane & 15);
                    if (gm < n_nodes)
                        support[(size_t)gm * OUT_F + gn] = (bf16)acc[m][n][j];
                }
            }
        }
        __syncthreads();   // all reads of As done before next rep rewrites
    }
}

// ---- kernel 3 (x4 instrumented): atomic-free CSR scatter -------------------
__global__ __launch_bounds__(256, 8) void scatter_x4_kernel(const int* __restrict__ adj_row,
                                                            const int* __restrict__ adj_col,
                                                            const float* __restrict__ adj_vals,
                                                            const bf16* __restrict__ support,
                                                            const int* __restrict__ row_ptr,
                                                            float* __restrict__ out,
                                                            int n_nodes) {
    __shared__ int   srow[WPB][PAGE];
    __shared__ int   scol[WPB][PAGE];
    __shared__ float sval[WPB][PAGE];

    const int t  = threadIdx.x & 63;
    const int w  = threadIdx.x >> 6;
    const int r0 = blockIdx.x * (WPB * RPW) + w * RPW;
    if (r0 >= n_nodes) return;                    // no barriers below: safe
    const int rEnd = min(r0 + RPW, n_nodes);
    const int eLo  = row_ptr[r0];
    const int eHi  = row_ptr[rEnd];

    for (int rep = 0; rep < SCAT_REP; ++rep) {
        float accx = 0.f, accy = 0.f;
        int   cur  = r0;

        auto flush_to = [&](int rNew) {   // wave-uniform
            if (cur < rEnd) {
                float2 st = {accx, accy};
                *reinterpret_cast<float2*>(out + (size_t)cur * OUT_F + t * 2) = st;
            }
            float2 z = {0.f, 0.f};
            int zhi = rNew < rEnd ? rNew : rEnd;
            for (int r = cur + 1; r < zhi; ++r)
                *reinterpret_cast<float2*>(out + (size_t)r * OUT_F + t * 2) = z;
            accx = 0.f; accy = 0.f;
            cur = rNew;
        };

        for (int base = eLo; base < eHi; base += PAGE) {
            const int nE = min(PAGE, eHi - base);
            for (int i = t; i < nE; i += 64) {    // per-wave staging, no barrier
                srow[w][i] = adj_row[base + i];
                scol[w][i] = adj_col[base + i];
                sval[w][i] = adj_vals[base + i];
            }
            const int nEpad = (nE + UNR - 1) & ~(UNR - 1);
            {
                int i = nE + t;                   // pad last batch: sentinel row
                if (i < nEpad) {
                    srow[w][i] = n_nodes;
                    scol[w][i] = 0;
                    sval[w][i] = 0.f;
                }
            }

            for (int i0 = 0; i0 < nE; i0 += UNR) {
                unsigned int u[UNR];
                #pragma unroll
                for (int k = 0; k < UNR; ++k) {
                    int c = scol[w][i0 + k];
                    u[k] = *reinterpret_cast<const unsigned int*>(support + (size_t)c * OUT_F + t * 2);
                }
                #pragma unroll
                for (int k = 0; k < UNR; ++k) {
                    int r = srow[w][i0 + k];
                    if (r != cur) flush_to(r);
                    float  s = sval[w][i0 + k];
                    bf16x2 v = __builtin_bit_cast(bf16x2, u[k]);
                    accx += s * (float)v[0];
                    accy += s * (float)v[1];
                }
            }
        }
        flush_to(rEnd);
    }
}

extern "C" void kernel_launch(void* const* d_in, const int* in_sizes, int n_in,
                              void* d_out, int out_size, void* d_ws, size_t ws_size,
                              hipStream_t stream) {
    const float* x        = (const float*)d_in[0];
    const int*   adj_row  = (const int*)d_in[1];
    const int*   adj_col  = (const int*)d_in[2];
    const float* adj_vals = (const float*)d_in[3];
    const float* weight   = (const float*)d_in[4];
    float*       out      = (float*)d_out;

    const int n_nodes = in_sizes[0] / IN_F;      // 100000
    const int n_edges = in_sizes[1];             // 1600000

    char* ws = (char*)d_ws;
    bf16* support = (bf16*)ws;                                    // 25.6 MB
    bf16* wt_frag = (bf16*)(ws + (size_t)n_nodes * OUT_F * 2);    // 128 KB
    int*  row_ptr = (int*)(ws + (size_t)n_nodes * OUT_F * 2 + IN_F * OUT_F * 2);  // 400 KB

    wt_convert_kernel<<<(IN_F * OUT_F) / 256, 256, 0, stream>>>(weight, wt_frag);

    row_ptr_kernel<<<(n_edges + 255) / 256, 256, 0, stream>>>(adj_row, row_ptr,
                                                              n_edges, n_nodes);

    int gemm_blocks = (n_nodes + BM - 1) / BM;   // 1563
    gemm_x6_kernel<<<gemm_blocks, 256, 0, stream>>>(x, wt_frag, support, n_nodes);

    int scat_blocks = (n_nodes + WPB * RPW - 1) / (WPB * RPW);  // 3125
    scatter_x4_kernel<<<scat_blocks, WPB * 64, 0, stream>>>(adj_row, adj_col, adj_vals,
                                                            support, row_ptr, out, n_nodes);
}

// Round 9
// 121.692 us; speedup vs baseline: 3.8324x; 3.8324x over previous
//
#include <hip/hip_runtime.h>
#include <hip/hip_bf16.h>

typedef __bf16 bf16;
typedef __attribute__((ext_vector_type(8))) __bf16 bf16x8;
typedef __attribute__((ext_vector_type(4))) __bf16 bf16x4;
typedef __attribute__((ext_vector_type(2))) __bf16 bf16x2;
typedef __attribute__((ext_vector_type(4))) float f32x4;

#define IN_F 512
#define OUT_F 128
#define BM 64
#define BK 64
#define NKT (IN_F / BK)
#define RPW 8       // rows per wave (scatter)
#define WPB 4       // waves per scatter block
#define PAGE 256    // edges staged per wave page
#define UNR 16
#define WT_BLOCKS 256

// ---- kernel 1: fused setup: wt_frag pack + row_ptr build ------------------
__global__ __launch_bounds__(256) void setup_kernel(const float* __restrict__ w,
                                                    bf16* __restrict__ wt_frag,
                                                    const int* __restrict__ adj_row,
                                                    int* __restrict__ row_ptr,
                                                    int n_edges, int n_nodes) {
    if (blockIdx.x < WT_BLOCKS) {
        // wt_frag layout: [kt(8)][kk(2)][nb(8)] fragments of 64 lanes x bf16x8
        int o = blockIdx.x * 256 + threadIdx.x;     // 0..65535
        int e   = o & 7;
        int l   = (o >> 3) & 63;
        int nb  = (o >> 9) & 7;
        int kkt = o >> 12;                          // kt*2+kk, 0..15
        int n = nb * 16 + (l & 15);
        int k = (kkt >> 1) * 64 + (kkt & 1) * 32 + (l >> 4) * 8 + e;
        wt_frag[o] = (bf16)w[k * OUT_F + n];
    } else {
        int e = (blockIdx.x - WT_BLOCKS) * 256 + threadIdx.x;
        if (e >= n_edges) return;
        int r1 = adj_row[e];
        int r0 = (e == 0) ? -1 : adj_row[e - 1];
        for (int r = r0 + 1; r <= r1; ++r) row_ptr[r] = e;
        if (e == n_edges - 1)
            for (int r = r1 + 1; r <= n_nodes; ++r) row_ptr[r] = n_edges;
    }
}

// ---- kernel 2: support = bf16(x @ W), depth-3 A-prefetch -------------------
// 64x128 tile, 4 waves (each 64 rows x 32 cols), 16x16x32 bf16 MFMA.
// A: 3 reg-staging sets (tiles kt+1..kt+3 in flight) -> ~2.3 iters of HBM
//    latency cover; fp32->bf16 cvt fused into ds_write; XOR-swizzled LDS dbuf.
// B: L2-hot fragment-packed, prefetched one K-step ahead so the B-wait before
//    MFMA is OLDER than the in-flight A loads (no transitive drain).
// Full unroll over NKT: all av[]/bfr[] indices compile-time (no scratch).
__global__ __launch_bounds__(256) void gemm_kernel(const float* __restrict__ x,
                                                   const bf16* __restrict__ wt_frag,
                                                   bf16* __restrict__ support,
                                                   int n_nodes) {
    __shared__ bf16 As[2][BM * BK];     // 2 x 8 KB

    const int tid  = threadIdx.x;
    const int lane = tid & 63;
    const int wid  = tid >> 6;          // wave owns cols [wid*32, wid*32+32)
    const int row0 = blockIdx.x * BM;

    float4 av[3][4];                    // 3 in-flight A tiles (fp32)
    bf16x8 bfr[2][2][2];                // B frags, double-buffered by kt&1

    auto load_tile = [&](int set, int kt) {
        const int k0 = kt * BK;
        #pragma unroll
        for (int i = 0; i < 4; ++i) {           // A: 64 rows x 16 float4
            int li = i * 256 + tid;
            int r = li >> 4, c4 = li & 15;
            int grow = row0 + r;
            float4 v = {0.f, 0.f, 0.f, 0.f};
            if (grow < n_nodes)
                v = *reinterpret_cast<const float4*>(x + (size_t)grow * IN_F + k0 + c4 * 4);
            av[set][i] = v;
        }
    };

    auto load_b = [&](int p, int kt) {
        #pragma unroll
        for (int kk = 0; kk < 2; ++kk)
            #pragma unroll
            for (int n = 0; n < 2; ++n) {
                int f = (kt * 2 + kk) * 8 + (wid * 2 + n);
                bfr[p][kk][n] = *reinterpret_cast<const bf16x8*>(wt_frag + ((size_t)f * 64 + lane) * 8);
            }
    };

    auto write_tile = [&](int set, int buf) {
        char* Ab = (char*)As[buf];
        #pragma unroll
        for (int i = 0; i < 4; ++i) {
            int li = i * 256 + tid;
            int r = li >> 4, c4 = li & 15;
            bf16x4 b;
            b[0] = (bf16)av[set][i].x; b[1] = (bf16)av[set][i].y;
            b[2] = (bf16)av[set][i].z; b[3] = (bf16)av[set][i].w;
            *reinterpret_cast<bf16x4*>(Ab + ((r * 128 + c4 * 8) ^ ((r & 7) << 4))) = b;
        }
    };

    // prologue: tile0 -> LDS; tiles 1,2 + B(0) in flight
    load_tile(0, 0);
    write_tile(0, 0);          // waits tile0 only (startup)
    load_tile(1, 1);
    load_tile(2, 2);
    load_b(0, 0);
    __syncthreads();

    f32x4 acc[4][2] = {};

    #pragma unroll
    for (int kt = 0; kt < NKT; ++kt) {
        // prefetch next B (kept newer than nothing it blocks) and A(kt+3)
        if (kt + 1 < NKT) load_b((kt + 1) & 1, kt + 1);
        if (kt + 3 < NKT) load_tile(kt % 3, kt + 3);   // av[kt%3] freed last iter

        // MFMA(kt): waits B(kt) (oldest in flight) -> A(kt+1..3) stay in flight
        const char* Ab = (const char*)As[kt & 1];
        #pragma unroll
        for (int kk = 0; kk < 2; ++kk) {
            const int kbyte = kk * 64 + (lane >> 4) * 16;
            bf16x8 a[4];
            #pragma unroll
            for (int m = 0; m < 4; ++m) {
                int r = m * 16 + (lane & 15);
                a[m] = *reinterpret_cast<const bf16x8*>(Ab + ((r * 128 + kbyte) ^ ((r & 7) << 4)));
            }
            #pragma unroll
            for (int m = 0; m < 4; ++m)
                #pragma unroll
                for (int n = 0; n < 2; ++n)
                    acc[m][n] = __builtin_amdgcn_mfma_f32_16x16x32_bf16(a[m], bfr[kt & 1][kk][n], acc[m][n], 0, 0, 0);
        }

        if (kt + 1 < NKT) {
            write_tile((kt + 1) % 3, (kt + 1) & 1);    // waits A(kt+1): ~2.3 iters old
            __syncthreads();
        }
    }

    // ---- epilogue: C/D layout col=lane&15, row=(lane>>4)*4+j -------------
    #pragma unroll
    for (int m = 0; m < 4; ++m) {
        #pragma unroll
        for (int n = 0; n < 2; ++n) {
            #pragma unroll
            for (int j = 0; j < 4; ++j) {
                int gm = row0 + m * 16 + (lane >> 4) * 4 + j;
                int gn = wid * 32 + n * 16 + (lane & 15);
                if (gm < n_nodes)
                    support[(size_t)gm * OUT_F + gn] = (bf16)acc[m][n][j];
            }
        }
    }
}

// ---- kernel 3: atomic-free CSR scatter, 4 independent waves/block ---------
__global__ __launch_bounds__(256, 8) void scatter_kernel(const int* __restrict__ adj_row,
                                                         const int* __restrict__ adj_col,
                                                         const float* __restrict__ adj_vals,
                                                         const bf16* __restrict__ support,
                                                         const int* __restrict__ row_ptr,
                                                         float* __restrict__ out,
                                                         int n_nodes) {
    __shared__ int   srow[WPB][PAGE];
    __shared__ int   scol[WPB][PAGE];
    __shared__ float sval[WPB][PAGE];

    const int t  = threadIdx.x & 63;
    const int w  = threadIdx.x >> 6;
    const int r0 = blockIdx.x * (WPB * RPW) + w * RPW;
    if (r0 >= n_nodes) return;                    // no barriers below: safe
    const int rEnd = min(r0 + RPW, n_nodes);
    const int eLo  = row_ptr[r0];
    const int eHi  = row_ptr[rEnd];

    float accx = 0.f, accy = 0.f;
    int   cur  = r0;          // row being accumulated; all rows < cur stored

    auto flush_to = [&](int rNew) {   // wave-uniform
        if (cur < rEnd) {
            float2 st = {accx, accy};
            *reinterpret_cast<float2*>(out + (size_t)cur * OUT_F + t * 2) = st;
        }
        float2 z = {0.f, 0.f};
        int zhi = rNew < rEnd ? rNew : rEnd;
        for (int r = cur + 1; r < zhi; ++r)
            *reinterpret_cast<float2*>(out + (size_t)r * OUT_F + t * 2) = z;
        accx = 0.f; accy = 0.f;
        cur = rNew;
    };

    for (int base = eLo; base < eHi; base += PAGE) {
        const int nE = min(PAGE, eHi - base);
        for (int i = t; i < nE; i += 64) {        // per-wave staging, no barrier
            srow[w][i] = adj_row[base + i];
            scol[w][i] = adj_col[base + i];
            sval[w][i] = adj_vals[base + i];
        }
        const int nEpad = (nE + UNR - 1) & ~(UNR - 1);
        {
            int i = nE + t;                       // pad last batch: sentinel row
            if (i < nEpad) {
                srow[w][i] = n_nodes;             // > any real row: forces flush
                scol[w][i] = 0;
                sval[w][i] = 0.f;
            }
        }

        for (int i0 = 0; i0 < nE; i0 += UNR) {
            // phase 1: UNR independent gathers in flight (raw bf16x2 as uint)
            unsigned int u[UNR];
            #pragma unroll
            for (int k = 0; k < UNR; ++k) {
                int c = scol[w][i0 + k];
                u[k] = *reinterpret_cast<const unsigned int*>(support + (size_t)c * OUT_F + t * 2);
            }
            // phase 2: serial run-accumulate (wave-uniform branches)
            #pragma unroll
            for (int k = 0; k < UNR; ++k) {
                int r = srow[w][i0 + k];
                if (r != cur) flush_to(r);
                float  s = sval[w][i0 + k];
                bf16x2 v = __builtin_bit_cast(bf16x2, u[k]);
                accx += s * (float)v[0];
                accy += s * (float)v[1];
            }
        }
    }
    flush_to(rEnd);   // store last accumulated row + zero-fill trailing rows
}

extern "C" void kernel_launch(void* const* d_in, const int* in_sizes, int n_in,
                              void* d_out, int out_size, void* d_ws, size_t ws_size,
                              hipStream_t stream) {
    const float* x        = (const float*)d_in[0];
    const int*   adj_row  = (const int*)d_in[1];
    const int*   adj_col  = (const int*)d_in[2];
    const float* adj_vals = (const float*)d_in[3];
    const float* weight   = (const float*)d_in[4];
    float*       out      = (float*)d_out;

    const int n_nodes = in_sizes[0] / IN_F;      // 100000
    const int n_edges = in_sizes[1];             // 1600000

    char* ws = (char*)d_ws;
    bf16* support = (bf16*)ws;                                    // 25.6 MB
    bf16* wt_frag = (bf16*)(ws + (size_t)n_nodes * OUT_F * 2);    // 128 KB
    int*  row_ptr = (int*)(ws + (size_t)n_nodes * OUT_F * 2 + IN_F * OUT_F * 2);  // 400 KB

    int setup_blocks = WT_BLOCKS + (n_edges + 255) / 256;
    setup_kernel<<<setup_blocks, 256, 0, stream>>>(weight, wt_frag, adj_row,
                                                   row_ptr, n_edges, n_nodes);

    int gemm_blocks = (n_nodes + BM - 1) / BM;   // 1563
    gemm_kernel<<<gemm_blocks, 256, 0, stream>>>(x, wt_frag, support, n_nodes);

    int scat_blocks = (n_nodes + WPB * RPW - 1) / (WPB * RPW);  // 3125
    scatter_kernel<<<scat_blocks, WPB * 64, 0, stream>>>(adj_row, adj_col, adj_vals,
                                                         support, row_ptr, out, n_nodes);
}